// Round 16
// baseline (205.988 us; speedup 1.0000x reference)
//
#include <hip/hip_runtime.h>
#include <cstddef>

typedef short short8 __attribute__((ext_vector_type(8)));
typedef unsigned short ushortx8 __attribute__((ext_vector_type(8)));
typedef unsigned short ushortx4 __attribute__((ext_vector_type(4)));
typedef float floatx4 __attribute__((ext_vector_type(4)));

__device__ __forceinline__ unsigned int bf16_rne(float x) {
    unsigned int u = __float_as_uint(x);
    return (u + 0x7fffu + ((u >> 16) & 1u)) >> 16;
}

__device__ __forceinline__ void split4(const floatx4 v,
                                       unsigned long long& hp,
                                       unsigned long long& lp) {
    unsigned int h[4], l[4];
    #pragma unroll
    for (int j = 0; j < 4; ++j) {
        h[j] = bf16_rne(v[j]);
        float hf = __uint_as_float(h[j] << 16);
        l[j] = bf16_rne(v[j] - hf);
    }
    hp = (unsigned long long)(h[0] | (h[1] << 16)) |
         ((unsigned long long)(h[2] | (h[3] << 16)) << 32);
    lp = (unsigned long long)(l[0] | (l[1] << 16)) |
         ((unsigned long long)(l[2] | (l[3] << 16)) << 32);
}

__device__ __forceinline__ unsigned long long pack_hi4(const floatx4 v) {
    unsigned int h0 = bf16_rne(v[0]), h1 = bf16_rne(v[1]);
    unsigned int h2 = bf16_rne(v[2]), h3 = bf16_rne(v[3]);
    return (unsigned long long)(h0 | (h1 << 16)) |
           ((unsigned long long)(h2 | (h3 << 16)) << 32);
}

__device__ __forceinline__ unsigned int xcd_swz(unsigned int flat, unsigned int nwg) {
    unsigned int qq = nwg >> 3, rr = nwg & 7;
    unsigned int xcd = flat & 7, idx = flat >> 3;
    return (xcd < rr) ? (xcd * (qq + 1) + idx)
                      : (rr * (qq + 1) + (xcd - rr) * qq + idx);
}

// ---------------------------------------------------------------------------
// Combined prep: blocks 0..831 = the six weight transpose+splits;
// blocks 832.. = grid-stride fp32->bf16 hi/lo conversion of x_T and x_S.
// ---------------------------------------------------------------------------
__global__ __launch_bounds__(256)
void prep_all(const float* __restrict__ WqT, const float* __restrict__ WkT,
              const float* __restrict__ Wv,  const float* __restrict__ WqS,
              const float* __restrict__ WkS, const float* __restrict__ Wout,
              unsigned short* __restrict__ wqkT_h, unsigned short* __restrict__ wqkT_l,
              unsigned short* __restrict__ wvt_h,  unsigned short* __restrict__ wvt_l,
              unsigned short* __restrict__ wqks_h, unsigned short* __restrict__ wqks_l,
              unsigned short* __restrict__ wout_h, unsigned short* __restrict__ wout_l,
              const float* __restrict__ xT, const float* __restrict__ xS, long n,
              unsigned short* __restrict__ xT_h, unsigned short* __restrict__ xT_l,
              unsigned short* __restrict__ xS_h, unsigned short* __restrict__ xS_l)
{
    const int tid = threadIdx.x;
    if (blockIdx.x < 832) {
        int bid = blockIdx.x;
        const float* in; unsigned short *oh, *ol;
        int C, rowOff, ldo, gxx;
        if (bid < 32)       { in = WqT;  oh = wqkT_h; ol = wqkT_l; C = 64;  rowOff = 0;   ldo = 512;  gxx = 2;  }
        else if (bid < 64)  { in = WkT;  oh = wqkT_h; ol = wqkT_l; C = 64;  rowOff = 64;  ldo = 512;  gxx = 2;  bid -= 32;  }
        else if (bid < 320) { in = Wv;   oh = wvt_h;  ol = wvt_l;  C = 512; rowOff = 0;   ldo = 512;  gxx = 16; bid -= 64;  }
        else if (bid < 448) { in = WqS;  oh = wqks_h; ol = wqks_l; C = 128; rowOff = 0;   ldo = 1024; gxx = 4;  bid -= 320; }
        else if (bid < 576) { in = WkS;  oh = wqks_h; ol = wqks_l; C = 128; rowOff = 128; ldo = 1024; gxx = 4;  bid -= 448; }
        else                { in = Wout; oh = wout_h; ol = wout_l; C = 512; rowOff = 0;   ldo = 512;  gxx = 16; bid -= 576; }

        __shared__ float tile[32][33];
        const int tc = (bid % gxx) * 32, tr = (bid / gxx) * 32;
        const int x = tid & 31, y = tid >> 5;
        #pragma unroll
        for (int i = 0; i < 32; i += 8)
            tile[y + i][x] = in[(long)(tr + y + i) * C + tc + x];
        __syncthreads();
        #pragma unroll
        for (int i = 0; i < 32; i += 8) {
            float v = tile[x][y + i];
            unsigned int h = bf16_rne(v);
            float hf = __uint_as_float(h << 16);
            unsigned int lo = bf16_rne(v - hf);
            long idx = (long)(tc + y + i + rowOff) * ldo + tr + x;
            oh[idx] = (unsigned short)h;
            ol[idx] = (unsigned short)lo;
        }
        return;
    }
    long n4 = n >> 2;
    long tot = n4 * 2;
    long nconv = (long)(gridDim.x - 832) * 256;
    for (long i = (long)(blockIdx.x - 832) * 256 + tid; i < tot; i += nconv) {
        bool second = i >= n4;
        long e = (second ? i - n4 : i) << 2;
        const float* src = second ? xS : xT;
        unsigned short* H = second ? xS_h : xT_h;
        unsigned short* L = second ? xS_l : xT_l;
        floatx4 v = *(const floatx4*)(src + e);
        ushortx4 h4, l4;
        #pragma unroll
        for (int j = 0; j < 4; ++j) {
            unsigned int h = bf16_rne(v[j]);
            float hf = __uint_as_float(h << 16);
            h4[j] = (unsigned short)h;
            l4[j] = (unsigned short)bf16_rne(v[j] - hf);
        }
        *(ushortx4*)(H + e) = h4;
        *(ushortx4*)(L + e) = l4;
    }
}

// ---------------------------------------------------------------------------
// NT GEMM: reg prefetch + LDS dbuf, batch-folded XCD swizzle.
// Grid = (N/BN, (M/BM)*nbatch, 1), mtiles = M/BM.
// ---------------------------------------------------------------------------
template<int BM, int BN, int AMODE, int BMODE, int OUTMODE, bool HASBIAS>
__global__ __launch_bounds__(256, 4)
void gemm_nt(const void* __restrict__ Ah_, const void* __restrict__ Al_,
             const void* __restrict__ Bh_, const void* __restrict__ Bl_,
             void* __restrict__ C_, void* __restrict__ Cl_,
             const float* __restrict__ bias,
             int K, int lda, int ldb, int ldc,
             long sA, long sB, long sC, float alpha, int nsplit, int mtiles)
{
    constexpr bool ALO = (AMODE == 1 || AMODE == 3);
    constexpr bool BLO = (BMODE == 1 || BMODE == 3);
    constexpr int LS = 40;
    __shared__ unsigned short Ash[2][BM][LS];
    __shared__ unsigned short Als[2][ALO ? BM : 1][LS];
    __shared__ unsigned short Bsh[2][BN][LS];
    __shared__ unsigned short Bls[2][BLO ? BN : 1][LS];

    const unsigned int gx = gridDim.x;
    unsigned int flat = xcd_swz(blockIdx.y * gx + blockIdx.x, gx * gridDim.y);
    const unsigned int perb = gx * (unsigned int)mtiles;
    const int b   = flat / perb;
    const unsigned int rm = flat % perb;
    const int bm0 = (rm / gx) * BM;
    const int bn0 = (rm % gx) * BN;
    const int tid  = threadIdx.x;
    const int lane = tid & 63;
    const int wid  = tid >> 6;
    const int wr = wid >> 1, wc = wid & 1;
    constexpr int WM = BM / 2, WN = BN / 2;
    constexpr int FM = WM / 16, FN = WN / 16;
    floatx4 acc[FM][FN] = {};
    const int l15  = lane & 15;
    const int koff = (lane >> 4) * 8;

    constexpr int ACHF = BM * 32 / 4, NAF0 = (ACHF + 255) / 256;
    constexpr int ACHH = BM * 32 / 8, NAH0 = (ACHH + 255) / 256;
    constexpr int BCHF = BN * 32 / 4, NBF0 = (BCHF + 255) / 256;
    constexpr int BCHH = BN * 32 / 8, NBH0 = (BCHH + 255) / 256;
    constexpr int NAF = (AMODE <= 1) ? NAF0 : 1;
    constexpr int NAH = (AMODE >= 2) ? NAH0 : 1;
    constexpr int NBF = (BMODE <= 1) ? NBF0 : 1;
    constexpr int NBH = (BMODE >= 2) ? NBH0 : 1;
    floatx4  aF[NAF], bF[NBF];
    ushortx8 aH[NAH], aL[NAH], bH[NBH], bL[NBH];

    auto loadA = [&](int k0) {
        if (AMODE <= 1) {
            const float* A = (const float*)Ah_ + (long)b * sA;
            #pragma unroll
            for (int i = 0; i < NAF; ++i) {
                int idx = i * 256 + tid;
                if (ACHF % 256 == 0 || idx < ACHF) {
                    int fc = idx * 4; int r = fc >> 5, c = fc & 31;
                    aF[i] = *(const floatx4*)(A + (long)(bm0 + r) * lda + k0 + c);
                }
            }
        } else {
            const unsigned short* A  = (const unsigned short*)Ah_ + (long)b * sA;
            const unsigned short* Al = (const unsigned short*)Al_ + (long)b * sA;
            #pragma unroll
            for (int i = 0; i < NAH; ++i) {
                int idx = i * 256 + tid;
                if (ACHH % 256 == 0 || idx < ACHH) {
                    int fc = idx * 8; int r = fc >> 5, c = fc & 31;
                    aH[i] = *(const ushortx8*)(A + (long)(bm0 + r) * lda + k0 + c);
                    if (AMODE == 3)
                        aL[i] = *(const ushortx8*)(Al + (long)(bm0 + r) * lda + k0 + c);
                }
            }
        }
    };
    auto loadB = [&](int k0) {
        if (BMODE <= 1) {
            const float* Bp = (const float*)Bh_ + (long)b * sB;
            #pragma unroll
            for (int i = 0; i < NBF; ++i) {
                int idx = i * 256 + tid;
                if (BCHF % 256 == 0 || idx < BCHF) {
                    int fc = idx * 4; int r = fc >> 5, c = fc & 31;
                    bF[i] = *(const floatx4*)(Bp + (long)(bn0 + r) * ldb + k0 + c);
                }
            }
        } else {
            const unsigned short* Bp = (const unsigned short*)Bh_ + (long)b * sB;
            const unsigned short* Bl = (const unsigned short*)Bl_ + (long)b * sB;
            #pragma unroll
            for (int i = 0; i < NBH; ++i) {
                int idx = i * 256 + tid;
                if (BCHH % 256 == 0 || idx < BCHH) {
                    int fc = idx * 8; int r = fc >> 5, c = fc & 31;
                    bH[i] = *(const ushortx8*)(Bp + (long)(bn0 + r) * ldb + k0 + c);
                    if (BMODE == 3)
                        bL[i] = *(const ushortx8*)(Bl + (long)(bn0 + r) * ldb + k0 + c);
                }
            }
        }
    };
    auto writeA = [&](int bf) {
        if (AMODE <= 1) {
            #pragma unroll
            for (int i = 0; i < NAF; ++i) {
                int idx = i * 256 + tid;
                if (ACHF % 256 == 0 || idx < ACHF) {
                    int fc = idx * 4; int r = fc >> 5, c = fc & 31;
                    if (AMODE == 1) {
                        unsigned long long hp, lp; split4(aF[i], hp, lp);
                        *(unsigned long long*)&Ash[bf][r][c] = hp;
                        *(unsigned long long*)&Als[bf][r][c] = lp;
                    } else {
                        *(unsigned long long*)&Ash[bf][r][c] = pack_hi4(aF[i]);
                    }
                }
            }
        } else {
            #pragma unroll
            for (int i = 0; i < NAH; ++i) {
                int idx = i * 256 + tid;
                if (ACHH % 256 == 0 || idx < ACHH) {
                    int fc = idx * 8; int r = fc >> 5, c = fc & 31;
                    *(ushortx8*)&Ash[bf][r][c] = aH[i];
                    if (AMODE == 3) *(ushortx8*)&Als[bf][r][c] = aL[i];
                }
            }
        }
    };
    auto writeB = [&](int bf) {
        if (BMODE <= 1) {
            #pragma unroll
            for (int i = 0; i < NBF; ++i) {
                int idx = i * 256 + tid;
                if (BCHF % 256 == 0 || idx < BCHF) {
                    int fc = idx * 4; int r = fc >> 5, c = fc & 31;
                    if (BMODE == 1) {
                        unsigned long long hp, lp; split4(bF[i], hp, lp);
                        *(unsigned long long*)&Bsh[bf][r][c] = hp;
                        *(unsigned long long*)&Bls[bf][r][c] = lp;
                    } else {
                        *(unsigned long long*)&Bsh[bf][r][c] = pack_hi4(bF[i]);
                    }
                }
            }
        } else {
            #pragma unroll
            for (int i = 0; i < NBH; ++i) {
                int idx = i * 256 + tid;
                if (BCHH % 256 == 0 || idx < BCHH) {
                    int fc = idx * 8; int r = fc >> 5, c = fc & 31;
                    *(ushortx8*)&Bsh[bf][r][c] = bH[i];
                    if (BMODE == 3) *(ushortx8*)&Bls[bf][r][c] = bL[i];
                }
            }
        }
    };
    auto compute = [&](int bf) {
        short8 ah[FM], al[FM], bh[FN], bl[FN];
        #pragma unroll
        for (int mi = 0; mi < FM; ++mi) {
            ah[mi] = *(const short8*)&Ash[bf][wr * WM + mi * 16 + l15][koff];
            if (ALO) al[mi] = *(const short8*)&Als[bf][wr * WM + mi * 16 + l15][koff];
        }
        #pragma unroll
        for (int ni = 0; ni < FN; ++ni) {
            bh[ni] = *(const short8*)&Bsh[bf][wc * WN + ni * 16 + l15][koff];
            if (BLO) bl[ni] = *(const short8*)&Bls[bf][wc * WN + ni * 16 + l15][koff];
        }
        #pragma unroll
        for (int mi = 0; mi < FM; ++mi)
            #pragma unroll
            for (int ni = 0; ni < FN; ++ni) {
                if (ALO)
                    acc[mi][ni] = __builtin_amdgcn_mfma_f32_16x16x32_bf16(
                        al[mi], bh[ni], acc[mi][ni], 0, 0, 0);
                if (BLO)
                    acc[mi][ni] = __builtin_amdgcn_mfma_f32_16x16x32_bf16(
                        ah[mi], bl[ni], acc[mi][ni], 0, 0, 0);
                acc[mi][ni] = __builtin_amdgcn_mfma_f32_16x16x32_bf16(
                    ah[mi], bh[ni], acc[mi][ni], 0, 0, 0);
            }
    };

    loadA(0); loadB(0);
    writeA(0); writeB(0);
    __syncthreads();
    int cur = 0;
    for (int k0 = 32; k0 < K; k0 += 32) {
        loadA(k0); loadB(k0);
        compute(cur);
        writeA(cur ^ 1); writeB(cur ^ 1);
        __syncthreads();
        cur ^= 1;
    }
    compute(cur);

    const int rq = (lane >> 4) * 4;
    #pragma unroll
    for (int mi = 0; mi < FM; ++mi) {
        #pragma unroll
        for (int ni = 0; ni < FN; ++ni) {
            int gm = bm0 + wr * WM + mi * 16 + rq;
            int gn = bn0 + wc * WN + ni * 16 + l15;
            float ae = (gn < nsplit) ? alpha : 1.0f;
            float be = 0.f;
            if (HASBIAS) be = (gn < nsplit) ? bias[gn] : 0.0f;
            float vals[4];
            #pragma unroll
            for (int j = 0; j < 4; ++j) vals[j] = acc[mi][ni][j] * ae + be;
            if (OUTMODE == 0) {
                float* C = (float*)C_ + (long)b * sC;
                #pragma unroll
                for (int j = 0; j < 4; ++j) C[(long)(gm + j) * ldc + gn] = vals[j];
            } else if (OUTMODE == 1) {
                float* C = (float*)C_ + (long)b * sC;
                floatx4 o;
                #pragma unroll
                for (int j = 0; j < 4; ++j) o[j] = vals[j];
                *(floatx4*)(C + (long)gn * ldc + gm) = o;
            } else if (OUTMODE == 2) {
                unsigned short* Ch = (unsigned short*)C_ + (long)b * sC;
                unsigned short* Cl = (unsigned short*)Cl_ + (long)b * sC;
                #pragma unroll
                for (int j = 0; j < 4; ++j) {
                    unsigned int h = bf16_rne(vals[j]);
                    float hf = __uint_as_float(h << 16);
                    unsigned int lo = bf16_rne(vals[j] - hf);
                    Ch[(long)(gm + j) * ldc + gn] = (unsigned short)h;
                    Cl[(long)(gm + j) * ldc + gn] = (unsigned short)lo;
                }
            } else {
                unsigned short* Ch = (unsigned short*)C_ + (long)b * sC;
                #pragma unroll
                for (int j = 0; j < 4; ++j)
                    Ch[(long)(gm + j) * ldc + gn] = (unsigned short)bf16_rne(vals[j]);
            }
        }
    }
}

// ---------------------------------------------------------------------------
// QK^T + row softmax -> P (bf16), XCD-swizzled. If TRANSP, write P^T.
// ---------------------------------------------------------------------------
template<int COLS, int DK, int LDQK, bool TRANSP>
__global__ __launch_bounds__(256, 2)
void qk_softmax(const unsigned short* __restrict__ qk_h,
                const unsigned short* __restrict__ qk_l,
                unsigned short* __restrict__ P)
{
    constexpr int WCOLS = COLS / 4;
    constexpr int FN = WCOLS / 16;
    constexpr int QPAD = DK + 24;
    __shared__ unsigned short Qh[32][QPAD];
    __shared__ unsigned short Ql[32][QPAD];
    __shared__ float red[32][4];
    __shared__ unsigned short Pl[32][COLS + 8];

    const unsigned int gx = gridDim.x;
    unsigned int flat = xcd_swz(blockIdx.y * gx + blockIdx.x, gx * gridDim.y);
    const int b  = flat / gx;
    const int q0 = (flat % gx) * 32;
    const long rowBase = (long)b * COLS;
    const int tid = threadIdx.x;
    const int lane = tid & 63, wid = tid >> 6;
    const int l15 = lane & 15, g = lane >> 4;
    const int koff = g * 8;

    constexpr int QCH = DK / 8;
    for (int i = tid; i < 32 * QCH; i += 256) {
        int r = i / QCH, c = (i % QCH) * 8;
        *(ushortx8*)&Qh[r][c] = *(const ushortx8*)(qk_h + (rowBase + q0 + r) * LDQK + c);
        *(ushortx8*)&Ql[r][c] = *(const ushortx8*)(qk_l + (rowBase + q0 + r) * LDQK + c);
    }
    __syncthreads();

    floatx4 acc[2][FN] = {};
    const unsigned short* kh = qk_h + rowBase * LDQK + DK;
    const unsigned short* kl = qk_l + rowBase * LDQK + DK;

    #pragma unroll
    for (int kk = 0; kk < DK; kk += 32) {
        short8 ah[2], al[2];
        #pragma unroll
        for (int mi = 0; mi < 2; ++mi) {
            ah[mi] = *(const short8*)&Qh[mi * 16 + l15][kk + koff];
            al[mi] = *(const short8*)&Ql[mi * 16 + l15][kk + koff];
        }
        #pragma unroll
        for (int ni = 0; ni < FN; ++ni) {
            long krow = wid * WCOLS + ni * 16 + l15;
            short8 bh = *(const short8*)(kh + krow * LDQK + kk + koff);
            short8 bl = *(const short8*)(kl + krow * LDQK + kk + koff);
            #pragma unroll
            for (int mi = 0; mi < 2; ++mi) {
                acc[mi][ni] = __builtin_amdgcn_mfma_f32_16x16x32_bf16(al[mi], bh, acc[mi][ni], 0, 0, 0);
                acc[mi][ni] = __builtin_amdgcn_mfma_f32_16x16x32_bf16(ah[mi], bl, acc[mi][ni], 0, 0, 0);
                acc[mi][ni] = __builtin_amdgcn_mfma_f32_16x16x32_bf16(ah[mi], bh, acc[mi][ni], 0, 0, 0);
            }
        }
    }

    float pm[2][4];
    #pragma unroll
    for (int mi = 0; mi < 2; ++mi)
        #pragma unroll
        for (int j = 0; j < 4; ++j) {
            float m = acc[mi][0][j];
            #pragma unroll
            for (int ni = 1; ni < FN; ++ni) m = fmaxf(m, acc[mi][ni][j]);
            pm[mi][j] = m;
        }
    #pragma unroll
    for (int msk = 1; msk < 16; msk <<= 1) {
        #pragma unroll
        for (int mi = 0; mi < 2; ++mi)
            #pragma unroll
            for (int j = 0; j < 4; ++j)
                pm[mi][j] = fmaxf(pm[mi][j], __shfl_xor(pm[mi][j], msk));
    }
    if (l15 == 0) {
        #pragma unroll
        for (int mi = 0; mi < 2; ++mi)
            #pragma unroll
            for (int j = 0; j < 4; ++j) red[mi * 16 + g * 4 + j][wid] = pm[mi][j];
    }
    __syncthreads();
    float rm[2][4];
    #pragma unroll
    for (int mi = 0; mi < 2; ++mi)
        #pragma unroll
        for (int j = 0; j < 4; ++j) {
            const float* r4 = red[mi * 16 + g * 4 + j];
            rm[mi][j] = fmaxf(fmaxf(r4[0], r4[1]), fmaxf(r4[2], r4[3]));
        }
    __syncthreads();

    float ps[2][4] = {};
    #pragma unroll
    for (int mi = 0; mi < 2; ++mi)
        #pragma unroll
        for (int ni = 0; ni < FN; ++ni)
            #pragma unroll
            for (int j = 0; j < 4; ++j) {
                float e = __expf(acc[mi][ni][j] - rm[mi][j]);
                acc[mi][ni][j] = e;
                ps[mi][j] += e;
            }
    #pragma unroll
    for (int msk = 1; msk < 16; msk <<= 1) {
        #pragma unroll
        for (int mi = 0; mi < 2; ++mi)
            #pragma unroll
            for (int j = 0; j < 4; ++j)
                ps[mi][j] += __shfl_xor(ps[mi][j], msk);
    }
    if (l15 == 0) {
        #pragma unroll
        for (int mi = 0; mi < 2; ++mi)
            #pragma unroll
            for (int j = 0; j < 4; ++j) red[mi * 16 + g * 4 + j][wid] = ps[mi][j];
    }
    __syncthreads();
    float inv[2][4];
    #pragma unroll
    for (int mi = 0; mi < 2; ++mi)
        #pragma unroll
        for (int j = 0; j < 4; ++j) {
            const float* r4 = red[mi * 16 + g * 4 + j];
            inv[mi][j] = 1.0f / (r4[0] + r4[1] + r4[2] + r4[3]);
        }

    #pragma unroll
    for (int mi = 0; mi < 2; ++mi)
        #pragma unroll
        for (int ni = 0; ni < FN; ++ni)
            #pragma unroll
            for (int j = 0; j < 4; ++j)
                Pl[mi * 16 + g * 4 + j][wid * WCOLS + ni * 16 + l15] =
                    (unsigned short)bf16_rne(acc[mi][ni][j] * inv[mi][j]);
    __syncthreads();

    if (TRANSP) {
        for (int i = tid; i < COLS * 4; i += 256) {
            int c = i >> 2;
            int rc = (i & 3) * 8;
            ushortx8 v;
            #pragma unroll
            for (int s = 0; s < 8; ++s) v[s] = Pl[rc + s][c];
            *(ushortx8*)(P + (rowBase + c) * COLS + q0 + rc) = v;
        }
    } else {
        constexpr int PCH = COLS / 8;
        for (int i = tid; i < 32 * PCH; i += 256) {
            int r = i / PCH, c = (i % PCH) * 8;
            *(ushortx8*)(P + (rowBase + q0 + r) * COLS + c) = *(const ushortx8*)&Pl[r][c];
        }
    }
}

extern "C" void kernel_launch(void* const* d_in, const int* in_sizes, int n_in,
                              void* d_out, int out_size, void* d_ws, size_t ws_size,
                              hipStream_t stream)
{
    (void)in_sizes; (void)n_in; (void)out_size; (void)ws_size;
    const float* x_T    = (const float*)d_in[0];
    const float* x_S    = (const float*)d_in[1];
    const float* Wq_T   = (const float*)d_in[2];
    const float* Wk_T   = (const float*)d_in[3];
    const float* Wv_T   = (const float*)d_in[4];
    const float* Wq_S   = (const float*)d_in[5];
    const float* Wk_S   = (const float*)d_in[6];
    const float* Wout_T = (const float*)d_in[7];
    const float* bout_T = (const float*)d_in[8];
    const float* bias_T = (const float*)d_in[9];
    const float* bias_S = (const float*)d_in[10];
    float* out = (float*)d_out;

    constexpr int B = 16, T = 1024, N = 512, DKT = 64, DKS = 128;
    typedef unsigned short us;

    char* w = (char*)d_ws;
    size_t off = 0;
    auto alloc = [&](size_t bytes) { char* p = w + off; off = (off + bytes + 255) & ~(size_t)255; return p; };
    us* wqkT_h = (us*)alloc(128 * 512 * 2);
    us* wqkT_l = (us*)alloc(128 * 512 * 2);
    us* wvt_h  = (us*)alloc(512 * 512 * 2);
    us* wvt_l  = (us*)alloc(512 * 512 * 2);
    us* wqks_h = (us*)alloc(256 * 1024 * 2);
    us* wqks_l = (us*)alloc(256 * 1024 * 2);
    us* wout_h = (us*)alloc(512 * 512 * 2);
    us* wout_l = (us*)alloc(512 * 512 * 2);
    us* qk_h   = (us*)alloc((size_t)16384 * 128 * 2);  // temporal q|k; spatial [8192][256]
    us* qk_l   = (us*)alloc((size_t)16384 * 128 * 2);
    us* P_T    = (us*)alloc((size_t)B * T * T * 2);    // 33.5 MB
    us* P_St   = (us*)alloc((size_t)B * N * N * 2);    // attn_S^T
    us* vT_h   = (us*)alloc((size_t)B * N * T * 2);    // v^T hi [b][n][t]
    us* M1t_h  = (us*)alloc((size_t)B * N * N * 2);    // [b][n][j]
    us* outT_h = (us*)alloc((size_t)B * T * N * 2);    // [b][t][n]
    us* xT_h   = (us*)alloc((size_t)16384 * 512 * 2);
    us* xT_l   = (us*)alloc((size_t)16384 * 512 * 2);
    us* xS_h   = (us*)alloc((size_t)16384 * 512 * 2);
    us* xS_l   = (us*)alloc((size_t)16384 * 512 * 2);

    const float scale_T = 0.125f;
    const float scale_S = 0.088388347648318447f;
    const int BIG = 1 << 30;
    const long XE = (long)16384 * 512;

    // 1. prep: weight transposes + x conversions in one launch
    prep_all<<<832 + 4096, 256, 0, stream>>>(
        Wq_T, Wk_T, Wv_T, Wq_S, Wk_S, Wout_T,
        wqkT_h, wqkT_l, wvt_h, wvt_l, wqks_h, wqks_l, wout_h, wout_l,
        x_T, x_S, XE, xT_h, xT_l, xS_h, xS_l);

    // ---- temporal chain ----
    // 2. qk = xT @ [Wq|Wk]^T  [M=16384 x N=128], K=512, 3-pass
    //    BM=32/BN=128 -> xT planes fetched exactly once (was x2 at BN=64)
    gemm_nt<32, 128, 3, 3, 2, true><<<dim3(1, 512), 256, 0, stream>>>(
        xT_h, xT_l, wqkT_h, wqkT_l, qk_h, qk_l, bias_T,
        512, 512, 512, 128, 0, 0, 0, scale_T, 64, 512);
    // 3. v^T_b = Wv^T @ x_b^T  [M=512 x N=1024], K=512, 2-pass, hi-only
    gemm_nt<64, 128, 3, 2, 3, false><<<dim3(8, 8 * B), 256, 0, stream>>>(
        wvt_h, wvt_l, xT_h, nullptr, vT_h, nullptr, nullptr,
        512, 512, 512, 1024, 0, (long)T * N, (long)N * T, 1.0f, 0, 8);
    // 4. logits_T + softmax -> P_T bf16
    qk_softmax<1024, 64, 128, false><<<dim3(32, 16), 256, 0, stream>>>(qk_h, qk_l, P_T);
    // 5. outT = P_T @ v  [M=1024 x N=512], K=1024, 1-pass, hi-only out
    gemm_nt<64, 128, 2, 2, 3, false><<<dim3(4, 16 * B), 256, 0, stream>>>(
        P_T, nullptr, vT_h, nullptr, outT_h, nullptr, nullptr,
        1024, 1024, 1024, 512, (long)T * T, (long)N * T, (long)T * N, 1.0f, 0, 16);

    // ---- spatial chain ----
    // 6. qkS = xS @ [WqS|WkS]^T  [M=8192 x N=256], K=1024, 3-pass
    //    BM=32/BN=128 -> xS planes fetched x2 (was x4 at BN=64)
    gemm_nt<32, 128, 3, 3, 2, true><<<dim3(2, 256), 256, 0, stream>>>(
        xS_h, xS_l, wqks_h, wqks_l, qk_h, qk_l, bias_S,
        1024, 1024, 1024, 256, 0, 0, 0, scale_S, 128, 256);
    // 7. logits_S + softmax -> P_S^T
    qk_softmax<512, 128, 256, true><<<dim3(16, 16), 256, 0, stream>>>(qk_h, qk_l, P_St);
    // 8. M1t[n][j] = sum_i Wout[i,n] * attnS[i,j]  [512 x 512], K=512, 2-pass, hi-only
    gemm_nt<64, 128, 3, 2, 3, false><<<dim3(4, 8 * B), 256, 0, stream>>>(
        wout_h, wout_l, P_St, nullptr, M1t_h, nullptr, nullptr,
        512, 512, 512, 512, 0, (long)N * N, (long)N * N, 1.0f, 0, 8);
    // 9. out[b,n,t] = (outT @ M1t^T + bout)^T  [M=1024 x N=512], K=512, STORE_T
    gemm_nt<64, 128, 2, 2, 1, true><<<dim3(4, 16 * B), 256, 0, stream>>>(
        outT_h, nullptr, M1t_h, nullptr, out, nullptr, bout_T,
        512, 512, 512, 1024, (long)T * N, (long)N * N, (long)N * T, 1.0f, BIG, 16);
}

// Round 17
// 199.922 us; speedup vs baseline: 1.0303x; 1.0303x over previous
//
#include <hip/hip_runtime.h>
#include <cstddef>

typedef short short8 __attribute__((ext_vector_type(8)));
typedef unsigned short ushortx8 __attribute__((ext_vector_type(8)));
typedef unsigned short ushortx4 __attribute__((ext_vector_type(4)));
typedef float floatx4 __attribute__((ext_vector_type(4)));

__device__ __forceinline__ unsigned int bf16_rne(float x) {
    unsigned int u = __float_as_uint(x);
    return (u + 0x7fffu + ((u >> 16) & 1u)) >> 16;
}

__device__ __forceinline__ void split4(const floatx4 v,
                                       unsigned long long& hp,
                                       unsigned long long& lp) {
    unsigned int h[4], l[4];
    #pragma unroll
    for (int j = 0; j < 4; ++j) {
        h[j] = bf16_rne(v[j]);
        float hf = __uint_as_float(h[j] << 16);
        l[j] = bf16_rne(v[j] - hf);
    }
    hp = (unsigned long long)(h[0] | (h[1] << 16)) |
         ((unsigned long long)(h[2] | (h[3] << 16)) << 32);
    lp = (unsigned long long)(l[0] | (l[1] << 16)) |
         ((unsigned long long)(l[2] | (l[3] << 16)) << 32);
}

__device__ __forceinline__ unsigned long long pack_hi4(const floatx4 v) {
    unsigned int h0 = bf16_rne(v[0]), h1 = bf16_rne(v[1]);
    unsigned int h2 = bf16_rne(v[2]), h3 = bf16_rne(v[3]);
    return (unsigned long long)(h0 | (h1 << 16)) |
           ((unsigned long long)(h2 | (h3 << 16)) << 32);
}

__device__ __forceinline__ unsigned int xcd_swz(unsigned int flat, unsigned int nwg) {
    unsigned int qq = nwg >> 3, rr = nwg & 7;
    unsigned int xcd = flat & 7, idx = flat >> 3;
    return (xcd < rr) ? (xcd * (qq + 1) + idx)
                      : (rr * (qq + 1) + (xcd - rr) * qq + idx);
}

// ---------------------------------------------------------------------------
// Combined prep: blocks 0..831 = the six weight transpose+splits;
// blocks 832.. = grid-stride fp32->bf16 hi/lo conversion of x_T and x_S.
// ---------------------------------------------------------------------------
__global__ __launch_bounds__(256)
void prep_all(const float* __restrict__ WqT, const float* __restrict__ WkT,
              const float* __restrict__ Wv,  const float* __restrict__ WqS,
              const float* __restrict__ WkS, const float* __restrict__ Wout,
              unsigned short* __restrict__ wqkT_h, unsigned short* __restrict__ wqkT_l,
              unsigned short* __restrict__ wvt_h,  unsigned short* __restrict__ wvt_l,
              unsigned short* __restrict__ wqks_h, unsigned short* __restrict__ wqks_l,
              unsigned short* __restrict__ wout_h, unsigned short* __restrict__ wout_l,
              const float* __restrict__ xT, const float* __restrict__ xS, long n,
              unsigned short* __restrict__ xT_h, unsigned short* __restrict__ xT_l,
              unsigned short* __restrict__ xS_h, unsigned short* __restrict__ xS_l)
{
    const int tid = threadIdx.x;
    if (blockIdx.x < 832) {
        int bid = blockIdx.x;
        const float* in; unsigned short *oh, *ol;
        int C, rowOff, ldo, gxx;
        if (bid < 32)       { in = WqT;  oh = wqkT_h; ol = wqkT_l; C = 64;  rowOff = 0;   ldo = 512;  gxx = 2;  }
        else if (bid < 64)  { in = WkT;  oh = wqkT_h; ol = wqkT_l; C = 64;  rowOff = 64;  ldo = 512;  gxx = 2;  bid -= 32;  }
        else if (bid < 320) { in = Wv;   oh = wvt_h;  ol = wvt_l;  C = 512; rowOff = 0;   ldo = 512;  gxx = 16; bid -= 64;  }
        else if (bid < 448) { in = WqS;  oh = wqks_h; ol = wqks_l; C = 128; rowOff = 0;   ldo = 1024; gxx = 4;  bid -= 320; }
        else if (bid < 576) { in = WkS;  oh = wqks_h; ol = wqks_l; C = 128; rowOff = 128; ldo = 1024; gxx = 4;  bid -= 448; }
        else                { in = Wout; oh = wout_h; ol = wout_l; C = 512; rowOff = 0;   ldo = 512;  gxx = 16; bid -= 576; }

        __shared__ float tile[32][33];
        const int tc = (bid % gxx) * 32, tr = (bid / gxx) * 32;
        const int x = tid & 31, y = tid >> 5;
        #pragma unroll
        for (int i = 0; i < 32; i += 8)
            tile[y + i][x] = in[(long)(tr + y + i) * C + tc + x];
        __syncthreads();
        #pragma unroll
        for (int i = 0; i < 32; i += 8) {
            float v = tile[x][y + i];
            unsigned int h = bf16_rne(v);
            float hf = __uint_as_float(h << 16);
            unsigned int lo = bf16_rne(v - hf);
            long idx = (long)(tc + y + i + rowOff) * ldo + tr + x;
            oh[idx] = (unsigned short)h;
            ol[idx] = (unsigned short)lo;
        }
        return;
    }
    long n4 = n >> 2;
    long tot = n4 * 2;
    long nconv = (long)(gridDim.x - 832) * 256;
    for (long i = (long)(blockIdx.x - 832) * 256 + tid; i < tot; i += nconv) {
        bool second = i >= n4;
        long e = (second ? i - n4 : i) << 2;
        const float* src = second ? xS : xT;
        unsigned short* H = second ? xS_h : xT_h;
        unsigned short* L = second ? xS_l : xT_l;
        floatx4 v = *(const floatx4*)(src + e);
        ushortx4 h4, l4;
        #pragma unroll
        for (int j = 0; j < 4; ++j) {
            unsigned int h = bf16_rne(v[j]);
            float hf = __uint_as_float(h << 16);
            h4[j] = (unsigned short)h;
            l4[j] = (unsigned short)bf16_rne(v[j] - hf);
        }
        *(ushortx4*)(H + e) = h4;
        *(ushortx4*)(L + e) = l4;
    }
}

// ---------------------------------------------------------------------------
// NT GEMM: reg prefetch + LDS dbuf, batch-folded XCD swizzle.
// Grid = (N/BN, (M/BM)*nbatch, 1), mtiles = M/BM.
// ---------------------------------------------------------------------------
template<int BM, int BN, int AMODE, int BMODE, int OUTMODE, bool HASBIAS>
__global__ __launch_bounds__(256, 4)
void gemm_nt(const void* __restrict__ Ah_, const void* __restrict__ Al_,
             const void* __restrict__ Bh_, const void* __restrict__ Bl_,
             void* __restrict__ C_, void* __restrict__ Cl_,
             const float* __restrict__ bias,
             int K, int lda, int ldb, int ldc,
             long sA, long sB, long sC, float alpha, int nsplit, int mtiles)
{
    constexpr bool ALO = (AMODE == 1 || AMODE == 3);
    constexpr bool BLO = (BMODE == 1 || BMODE == 3);
    constexpr int LS = 40;
    __shared__ unsigned short Ash[2][BM][LS];
    __shared__ unsigned short Als[2][ALO ? BM : 1][LS];
    __shared__ unsigned short Bsh[2][BN][LS];
    __shared__ unsigned short Bls[2][BLO ? BN : 1][LS];

    const unsigned int gx = gridDim.x;
    unsigned int flat = xcd_swz(blockIdx.y * gx + blockIdx.x, gx * gridDim.y);
    const unsigned int perb = gx * (unsigned int)mtiles;
    const int b   = flat / perb;
    const unsigned int rm = flat % perb;
    const int bm0 = (rm / gx) * BM;
    const int bn0 = (rm % gx) * BN;
    const int tid  = threadIdx.x;
    const int lane = tid & 63;
    const int wid  = tid >> 6;
    const int wr = wid >> 1, wc = wid & 1;
    constexpr int WM = BM / 2, WN = BN / 2;
    constexpr int FM = WM / 16, FN = WN / 16;
    floatx4 acc[FM][FN] = {};
    const int l15  = lane & 15;
    const int koff = (lane >> 4) * 8;

    constexpr int ACHF = BM * 32 / 4, NAF0 = (ACHF + 255) / 256;
    constexpr int ACHH = BM * 32 / 8, NAH0 = (ACHH + 255) / 256;
    constexpr int BCHF = BN * 32 / 4, NBF0 = (BCHF + 255) / 256;
    constexpr int BCHH = BN * 32 / 8, NBH0 = (BCHH + 255) / 256;
    constexpr int NAF = (AMODE <= 1) ? NAF0 : 1;
    constexpr int NAH = (AMODE >= 2) ? NAH0 : 1;
    constexpr int NBF = (BMODE <= 1) ? NBF0 : 1;
    constexpr int NBH = (BMODE >= 2) ? NBH0 : 1;
    floatx4  aF[NAF], bF[NBF];
    ushortx8 aH[NAH], aL[NAH], bH[NBH], bL[NBH];

    auto loadA = [&](int k0) {
        if (AMODE <= 1) {
            const float* A = (const float*)Ah_ + (long)b * sA;
            #pragma unroll
            for (int i = 0; i < NAF; ++i) {
                int idx = i * 256 + tid;
                if (ACHF % 256 == 0 || idx < ACHF) {
                    int fc = idx * 4; int r = fc >> 5, c = fc & 31;
                    aF[i] = *(const floatx4*)(A + (long)(bm0 + r) * lda + k0 + c);
                }
            }
        } else {
            const unsigned short* A  = (const unsigned short*)Ah_ + (long)b * sA;
            const unsigned short* Al = (const unsigned short*)Al_ + (long)b * sA;
            #pragma unroll
            for (int i = 0; i < NAH; ++i) {
                int idx = i * 256 + tid;
                if (ACHH % 256 == 0 || idx < ACHH) {
                    int fc = idx * 8; int r = fc >> 5, c = fc & 31;
                    aH[i] = *(const ushortx8*)(A + (long)(bm0 + r) * lda + k0 + c);
                    if (AMODE == 3)
                        aL[i] = *(const ushortx8*)(Al + (long)(bm0 + r) * lda + k0 + c);
                }
            }
        }
    };
    auto loadB = [&](int k0) {
        if (BMODE <= 1) {
            const float* Bp = (const float*)Bh_ + (long)b * sB;
            #pragma unroll
            for (int i = 0; i < NBF; ++i) {
                int idx = i * 256 + tid;
                if (BCHF % 256 == 0 || idx < BCHF) {
                    int fc = idx * 4; int r = fc >> 5, c = fc & 31;
                    bF[i] = *(const floatx4*)(Bp + (long)(bn0 + r) * ldb + k0 + c);
                }
            }
        } else {
            const unsigned short* Bp = (const unsigned short*)Bh_ + (long)b * sB;
            const unsigned short* Bl = (const unsigned short*)Bl_ + (long)b * sB;
            #pragma unroll
            for (int i = 0; i < NBH; ++i) {
                int idx = i * 256 + tid;
                if (BCHH % 256 == 0 || idx < BCHH) {
                    int fc = idx * 8; int r = fc >> 5, c = fc & 31;
                    bH[i] = *(const ushortx8*)(Bp + (long)(bn0 + r) * ldb + k0 + c);
                    if (BMODE == 3)
                        bL[i] = *(const ushortx8*)(Bl + (long)(bn0 + r) * ldb + k0 + c);
                }
            }
        }
    };
    auto writeA = [&](int bf) {
        if (AMODE <= 1) {
            #pragma unroll
            for (int i = 0; i < NAF; ++i) {
                int idx = i * 256 + tid;
                if (ACHF % 256 == 0 || idx < ACHF) {
                    int fc = idx * 4; int r = fc >> 5, c = fc & 31;
                    if (AMODE == 1) {
                        unsigned long long hp, lp; split4(aF[i], hp, lp);
                        *(unsigned long long*)&Ash[bf][r][c] = hp;
                        *(unsigned long long*)&Als[bf][r][c] = lp;
                    } else {
                        *(unsigned long long*)&Ash[bf][r][c] = pack_hi4(aF[i]);
                    }
                }
            }
        } else {
            #pragma unroll
            for (int i = 0; i < NAH; ++i) {
                int idx = i * 256 + tid;
                if (ACHH % 256 == 0 || idx < ACHH) {
                    int fc = idx * 8; int r = fc >> 5, c = fc & 31;
                    *(ushortx8*)&Ash[bf][r][c] = aH[i];
                    if (AMODE == 3) *(ushortx8*)&Als[bf][r][c] = aL[i];
                }
            }
        }
    };
    auto writeB = [&](int bf) {
        if (BMODE <= 1) {
            #pragma unroll
            for (int i = 0; i < NBF; ++i) {
                int idx = i * 256 + tid;
                if (BCHF % 256 == 0 || idx < BCHF) {
                    int fc = idx * 4; int r = fc >> 5, c = fc & 31;
                    if (BMODE == 1) {
                        unsigned long long hp, lp; split4(bF[i], hp, lp);
                        *(unsigned long long*)&Bsh[bf][r][c] = hp;
                        *(unsigned long long*)&Bls[bf][r][c] = lp;
                    } else {
                        *(unsigned long long*)&Bsh[bf][r][c] = pack_hi4(bF[i]);
                    }
                }
            }
        } else {
            #pragma unroll
            for (int i = 0; i < NBH; ++i) {
                int idx = i * 256 + tid;
                if (BCHH % 256 == 0 || idx < BCHH) {
                    int fc = idx * 8; int r = fc >> 5, c = fc & 31;
                    *(ushortx8*)&Bsh[bf][r][c] = bH[i];
                    if (BMODE == 3) *(ushortx8*)&Bls[bf][r][c] = bL[i];
                }
            }
        }
    };
    auto compute = [&](int bf) {
        short8 ah[FM], al[FM], bh[FN], bl[FN];
        #pragma unroll
        for (int mi = 0; mi < FM; ++mi) {
            ah[mi] = *(const short8*)&Ash[bf][wr * WM + mi * 16 + l15][koff];
            if (ALO) al[mi] = *(const short8*)&Als[bf][wr * WM + mi * 16 + l15][koff];
        }
        #pragma unroll
        for (int ni = 0; ni < FN; ++ni) {
            bh[ni] = *(const short8*)&Bsh[bf][wc * WN + ni * 16 + l15][koff];
            if (BLO) bl[ni] = *(const short8*)&Bls[bf][wc * WN + ni * 16 + l15][koff];
        }
        #pragma unroll
        for (int mi = 0; mi < FM; ++mi)
            #pragma unroll
            for (int ni = 0; ni < FN; ++ni) {
                if (ALO)
                    acc[mi][ni] = __builtin_amdgcn_mfma_f32_16x16x32_bf16(
                        al[mi], bh[ni], acc[mi][ni], 0, 0, 0);
                if (BLO)
                    acc[mi][ni] = __builtin_amdgcn_mfma_f32_16x16x32_bf16(
                        ah[mi], bl[ni], acc[mi][ni], 0, 0, 0);
                acc[mi][ni] = __builtin_amdgcn_mfma_f32_16x16x32_bf16(
                    ah[mi], bh[ni], acc[mi][ni], 0, 0, 0);
            }
    };

    loadA(0); loadB(0);
    writeA(0); writeB(0);
    __syncthreads();
    int cur = 0;
    for (int k0 = 32; k0 < K; k0 += 32) {
        loadA(k0); loadB(k0);
        compute(cur);
        writeA(cur ^ 1); writeB(cur ^ 1);
        __syncthreads();
        cur ^= 1;
    }
    compute(cur);

    const int rq = (lane >> 4) * 4;
    #pragma unroll
    for (int mi = 0; mi < FM; ++mi) {
        #pragma unroll
        for (int ni = 0; ni < FN; ++ni) {
            int gm = bm0 + wr * WM + mi * 16 + rq;
            int gn = bn0 + wc * WN + ni * 16 + l15;
            float ae = (gn < nsplit) ? alpha : 1.0f;
            float be = 0.f;
            if (HASBIAS) be = (gn < nsplit) ? bias[gn] : 0.0f;
            float vals[4];
            #pragma unroll
            for (int j = 0; j < 4; ++j) vals[j] = acc[mi][ni][j] * ae + be;
            if (OUTMODE == 0) {
                float* C = (float*)C_ + (long)b * sC;
                #pragma unroll
                for (int j = 0; j < 4; ++j) C[(long)(gm + j) * ldc + gn] = vals[j];
            } else if (OUTMODE == 1) {
                float* C = (float*)C_ + (long)b * sC;
                floatx4 o;
                #pragma unroll
                for (int j = 0; j < 4; ++j) o[j] = vals[j];
                *(floatx4*)(C + (long)gn * ldc + gm) = o;
            } else if (OUTMODE == 2) {
                unsigned short* Ch = (unsigned short*)C_ + (long)b * sC;
                unsigned short* Cl = (unsigned short*)Cl_ + (long)b * sC;
                #pragma unroll
                for (int j = 0; j < 4; ++j) {
                    unsigned int h = bf16_rne(vals[j]);
                    float hf = __uint_as_float(h << 16);
                    unsigned int lo = bf16_rne(vals[j] - hf);
                    Ch[(long)(gm + j) * ldc + gn] = (unsigned short)h;
                    Cl[(long)(gm + j) * ldc + gn] = (unsigned short)lo;
                }
            } else {
                unsigned short* Ch = (unsigned short*)C_ + (long)b * sC;
                #pragma unroll
                for (int j = 0; j < 4; ++j)
                    Ch[(long)(gm + j) * ldc + gn] = (unsigned short)bf16_rne(vals[j]);
            }
        }
    }
}

// ---------------------------------------------------------------------------
// QK^T + row softmax -> P (bf16), XCD-swizzled. If TRANSP, write P^T.
// ---------------------------------------------------------------------------
template<int COLS, int DK, int LDQK, bool TRANSP>
__global__ __launch_bounds__(256, 2)
void qk_softmax(const unsigned short* __restrict__ qk_h,
                const unsigned short* __restrict__ qk_l,
                unsigned short* __restrict__ P)
{
    constexpr int WCOLS = COLS / 4;
    constexpr int FN = WCOLS / 16;
    constexpr int QPAD = DK + 24;
    __shared__ unsigned short Qh[32][QPAD];
    __shared__ unsigned short Ql[32][QPAD];
    __shared__ float red[32][4];
    __shared__ unsigned short Pl[32][COLS + 8];

    const unsigned int gx = gridDim.x;
    unsigned int flat = xcd_swz(blockIdx.y * gx + blockIdx.x, gx * gridDim.y);
    const int b  = flat / gx;
    const int q0 = (flat % gx) * 32;
    const long rowBase = (long)b * COLS;
    const int tid = threadIdx.x;
    const int lane = tid & 63, wid = tid >> 6;
    const int l15 = lane & 15, g = lane >> 4;
    const int koff = g * 8;

    constexpr int QCH = DK / 8;
    for (int i = tid; i < 32 * QCH; i += 256) {
        int r = i / QCH, c = (i % QCH) * 8;
        *(ushortx8*)&Qh[r][c] = *(const ushortx8*)(qk_h + (rowBase + q0 + r) * LDQK + c);
        *(ushortx8*)&Ql[r][c] = *(const ushortx8*)(qk_l + (rowBase + q0 + r) * LDQK + c);
    }
    __syncthreads();

    floatx4 acc[2][FN] = {};
    const unsigned short* kh = qk_h + rowBase * LDQK + DK;
    const unsigned short* kl = qk_l + rowBase * LDQK + DK;

    #pragma unroll
    for (int kk = 0; kk < DK; kk += 32) {
        short8 ah[2], al[2];
        #pragma unroll
        for (int mi = 0; mi < 2; ++mi) {
            ah[mi] = *(const short8*)&Qh[mi * 16 + l15][kk + koff];
            al[mi] = *(const short8*)&Ql[mi * 16 + l15][kk + koff];
        }
        #pragma unroll
        for (int ni = 0; ni < FN; ++ni) {
            long krow = wid * WCOLS + ni * 16 + l15;
            short8 bh = *(const short8*)(kh + krow * LDQK + kk + koff);
            short8 bl = *(const short8*)(kl + krow * LDQK + kk + koff);
            #pragma unroll
            for (int mi = 0; mi < 2; ++mi) {
                acc[mi][ni] = __builtin_amdgcn_mfma_f32_16x16x32_bf16(al[mi], bh, acc[mi][ni], 0, 0, 0);
                acc[mi][ni] = __builtin_amdgcn_mfma_f32_16x16x32_bf16(ah[mi], bl, acc[mi][ni], 0, 0, 0);
                acc[mi][ni] = __builtin_amdgcn_mfma_f32_16x16x32_bf16(ah[mi], bh, acc[mi][ni], 0, 0, 0);
            }
        }
    }

    float pm[2][4];
    #pragma unroll
    for (int mi = 0; mi < 2; ++mi)
        #pragma unroll
        for (int j = 0; j < 4; ++j) {
            float m = acc[mi][0][j];
            #pragma unroll
            for (int ni = 1; ni < FN; ++ni) m = fmaxf(m, acc[mi][ni][j]);
            pm[mi][j] = m;
        }
    #pragma unroll
    for (int msk = 1; msk < 16; msk <<= 1) {
        #pragma unroll
        for (int mi = 0; mi < 2; ++mi)
            #pragma unroll
            for (int j = 0; j < 4; ++j)
                pm[mi][j] = fmaxf(pm[mi][j], __shfl_xor(pm[mi][j], msk));
    }
    if (l15 == 0) {
        #pragma unroll
        for (int mi = 0; mi < 2; ++mi)
            #pragma unroll
            for (int j = 0; j < 4; ++j) red[mi * 16 + g * 4 + j][wid] = pm[mi][j];
    }
    __syncthreads();
    float rm[2][4];
    #pragma unroll
    for (int mi = 0; mi < 2; ++mi)
        #pragma unroll
        for (int j = 0; j < 4; ++j) {
            const float* r4 = red[mi * 16 + g * 4 + j];
            rm[mi][j] = fmaxf(fmaxf(r4[0], r4[1]), fmaxf(r4[2], r4[3]));
        }
    __syncthreads();

    float ps[2][4] = {};
    #pragma unroll
    for (int mi = 0; mi < 2; ++mi)
        #pragma unroll
        for (int ni = 0; ni < FN; ++ni)
            #pragma unroll
            for (int j = 0; j < 4; ++j) {
                float e = __expf(acc[mi][ni][j] - rm[mi][j]);
                acc[mi][ni][j] = e;
                ps[mi][j] += e;
            }
    #pragma unroll
    for (int msk = 1; msk < 16; msk <<= 1) {
        #pragma unroll
        for (int mi = 0; mi < 2; ++mi)
            #pragma unroll
            for (int j = 0; j < 4; ++j)
                ps[mi][j] += __shfl_xor(ps[mi][j], msk);
    }
    if (l15 == 0) {
        #pragma unroll
        for (int mi = 0; mi < 2; ++mi)
            #pragma unroll
            for (int j = 0; j < 4; ++j) red[mi * 16 + g * 4 + j][wid] = ps[mi][j];
    }
    __syncthreads();
    float inv[2][4];
    #pragma unroll
    for (int mi = 0; mi < 2; ++mi)
        #pragma unroll
        for (int j = 0; j < 4; ++j) {
            const float* r4 = red[mi * 16 + g * 4 + j];
            inv[mi][j] = 1.0f / (r4[0] + r4[1] + r4[2] + r4[3]);
        }

    #pragma unroll
    for (int mi = 0; mi < 2; ++mi)
        #pragma unroll
        for (int ni = 0; ni < FN; ++ni)
            #pragma unroll
            for (int j = 0; j < 4; ++j)
                Pl[mi * 16 + g * 4 + j][wid * WCOLS + ni * 16 + l15] =
                    (unsigned short)bf16_rne(acc[mi][ni][j] * inv[mi][j]);
    __syncthreads();

    if (TRANSP) {
        for (int i = tid; i < COLS * 4; i += 256) {
            int c = i >> 2;
            int rc = (i & 3) * 8;
            ushortx8 v;
            #pragma unroll
            for (int s = 0; s < 8; ++s) v[s] = Pl[rc + s][c];
            *(ushortx8*)(P + (rowBase + c) * COLS + q0 + rc) = v;
        }
    } else {
        constexpr int PCH = COLS / 8;
        for (int i = tid; i < 32 * PCH; i += 256) {
            int r = i / PCH, c = (i % PCH) * 8;
            *(ushortx8*)(P + (rowBase + q0 + r) * COLS + c) = *(const ushortx8*)&Pl[r][c];
        }
    }
}

extern "C" void kernel_launch(void* const* d_in, const int* in_sizes, int n_in,
                              void* d_out, int out_size, void* d_ws, size_t ws_size,
                              hipStream_t stream)
{
    (void)in_sizes; (void)n_in; (void)out_size; (void)ws_size;
    const float* x_T    = (const float*)d_in[0];
    const float* x_S    = (const float*)d_in[1];
    const float* Wq_T   = (const float*)d_in[2];
    const float* Wk_T   = (const float*)d_in[3];
    const float* Wv_T   = (const float*)d_in[4];
    const float* Wq_S   = (const float*)d_in[5];
    const float* Wk_S   = (const float*)d_in[6];
    const float* Wout_T = (const float*)d_in[7];
    const float* bout_T = (const float*)d_in[8];
    const float* bias_T = (const float*)d_in[9];
    const float* bias_S = (const float*)d_in[10];
    float* out = (float*)d_out;

    constexpr int B = 16, T = 1024, N = 512, DKT = 64, DKS = 128;
    typedef unsigned short us;

    char* w = (char*)d_ws;
    size_t off = 0;
    auto alloc = [&](size_t bytes) { char* p = w + off; off = (off + bytes + 255) & ~(size_t)255; return p; };
    us* wqkT_h = (us*)alloc(128 * 512 * 2);
    us* wqkT_l = (us*)alloc(128 * 512 * 2);
    us* wvt_h  = (us*)alloc(512 * 512 * 2);
    us* wvt_l  = (us*)alloc(512 * 512 * 2);
    us* wqks_h = (us*)alloc(256 * 1024 * 2);
    us* wqks_l = (us*)alloc(256 * 1024 * 2);
    us* wout_h = (us*)alloc(512 * 512 * 2);
    us* wout_l = (us*)alloc(512 * 512 * 2);
    us* qk_h   = (us*)alloc((size_t)16384 * 128 * 2);  // temporal q|k; spatial [8192][256]
    us* qk_l   = (us*)alloc((size_t)16384 * 128 * 2);
    us* P_T    = (us*)alloc((size_t)B * T * T * 2);    // 33.5 MB
    us* P_St   = (us*)alloc((size_t)B * N * N * 2);    // attn_S^T
    us* vT_h   = (us*)alloc((size_t)B * N * T * 2);    // v^T hi [b][n][t]
    us* M1t_h  = (us*)alloc((size_t)B * N * N * 2);    // [b][n][j]
    us* outT_h = (us*)alloc((size_t)B * T * N * 2);    // [b][t][n]
    us* xT_h   = (us*)alloc((size_t)16384 * 512 * 2);
    us* xT_l   = (us*)alloc((size_t)16384 * 512 * 2);
    us* xS_h   = (us*)alloc((size_t)16384 * 512 * 2);
    us* xS_l   = (us*)alloc((size_t)16384 * 512 * 2);

    const float scale_T = 0.125f;
    const float scale_S = 0.088388347648318447f;
    const int BIG = 1 << 30;
    const long XE = (long)16384 * 512;

    // 1. prep: weight transposes + x conversions in one launch
    prep_all<<<832 + 4096, 256, 0, stream>>>(
        Wq_T, Wk_T, Wv_T, Wq_S, Wk_S, Wout_T,
        wqkT_h, wqkT_l, wvt_h, wvt_l, wqks_h, wqks_l, wout_h, wout_l,
        x_T, x_S, XE, xT_h, xT_l, xS_h, xS_l);

    // ---- temporal chain ----
    // 2. qk = xT @ [Wq|Wk]^T  [M=16384 x N=128], K=512, 3-pass
    gemm_nt<64, 64, 3, 3, 2, true><<<dim3(2, 256), 256, 0, stream>>>(
        xT_h, xT_l, wqkT_h, wqkT_l, qk_h, qk_l, bias_T,
        512, 512, 512, 128, 0, 0, 0, scale_T, 64, 256);
    // 3. v^T_b = Wv^T @ x_b^T  [M=512 x N=1024], K=512, 2-pass, hi-only
    gemm_nt<64, 128, 3, 2, 3, false><<<dim3(8, 8 * B), 256, 0, stream>>>(
        wvt_h, wvt_l, xT_h, nullptr, vT_h, nullptr, nullptr,
        512, 512, 512, 1024, 0, (long)T * N, (long)N * T, 1.0f, 0, 8);
    // 4. logits_T + softmax -> P_T bf16
    qk_softmax<1024, 64, 128, false><<<dim3(32, 16), 256, 0, stream>>>(qk_h, qk_l, P_T);
    // 5. outT = P_T @ v  [M=1024 x N=512], K=1024, 1-pass, hi-only out
    gemm_nt<64, 128, 2, 2, 3, false><<<dim3(4, 16 * B), 256, 0, stream>>>(
        P_T, nullptr, vT_h, nullptr, outT_h, nullptr, nullptr,
        1024, 1024, 1024, 512, (long)T * T, (long)N * T, (long)T * N, 1.0f, 0, 16);

    // ---- spatial chain ----
    // 6. qkS = xS @ [WqS|WkS]^T  [M=8192 x N=256], K=1024, 3-pass
    gemm_nt<64, 64, 3, 3, 2, true><<<dim3(4, 128), 256, 0, stream>>>(
        xS_h, xS_l, wqks_h, wqks_l, qk_h, qk_l, bias_S,
        1024, 1024, 1024, 256, 0, 0, 0, scale_S, 128, 128);
    // 7. logits_S + softmax -> P_S^T
    qk_softmax<512, 128, 256, true><<<dim3(16, 16), 256, 0, stream>>>(qk_h, qk_l, P_St);
    // 8. M1t[n][j] = sum_i Wout[i,n] * attnS[i,j]  [512 x 512], K=512, 2-pass, hi-only
    gemm_nt<64, 128, 3, 2, 3, false><<<dim3(4, 8 * B), 256, 0, stream>>>(
        wout_h, wout_l, P_St, nullptr, M1t_h, nullptr, nullptr,
        512, 512, 512, 512, 0, (long)N * N, (long)N * N, 1.0f, 0, 8);
    // 9. out[b,n,t] = (outT @ M1t^T + bout)^T  [M=1024 x N=512], K=512, STORE_T
    gemm_nt<64, 128, 2, 2, 1, true><<<dim3(4, 16 * B), 256, 0, stream>>>(
        outT_h, nullptr, M1t_h, nullptr, out, nullptr, bout_T,
        512, 512, 512, 1024, (long)T * N, (long)N * N, (long)N * T, 1.0f, BIG, 16);
}